// Round 2
// baseline (564.133 us; speedup 1.0000x reference)
//
#include <hip/hip_runtime.h>

// ---------------------------------------------------------------------------
// DTP_5377299055222: SE(3)-equivariant conv block, B=1, N=8192, K=32, H=16
// f32 in / f32 out.
// Kernels:
//   k_lin_in : xi/xj degreewise linears  (x @ w_xi, x @ w_xj)
//   k_wts    : transpose radial weights into a contiguous scratch blob
//              + neighbor_mask layout detection (bool-1B vs int32)
//   k_pairs  : per-(n,k) radial MLPs + pair einsums + masked mean over k
//   k_out    : output degreewise linears + self-interaction
// ---------------------------------------------------------------------------

#define NNODE 8192
#define KNBR  32

// workspace float offsets
#define XI0_OFF   0         // 8192*16
#define XJ0_OFF   131072
#define XI1_OFF   262144    // 8192*24
#define XJ1_OFF   458752
#define INT0_OFF  655360    // 8192*16
#define INT1_OFF  786432    // 8192*24
#define WTS_OFF   983040    // 7328 floats
#define FLAG_OFF  990400    // 1 int

// radial weight blob: per pair [w1 16][b1 16][g1 16][b2 16][g2 16][b3 C][w2t 256][w3t 16C]
// pair order 00,10,01,11 ; C = 128,64,64,96 ; bases 0,2512,3936,5360
#define BASE00 0
#define BASE10 2512
#define BASE01 3936
#define BASE11 5360

static __device__ __forceinline__ float fsilu(float x) {
    return x * (1.0f / (1.0f + __expf(-x)));
}

static __device__ __forceinline__ float dot16(const float* __restrict__ w, const float* h) {
    const float4* w4 = (const float4*)w;
    float4 a = w4[0], b = w4[1], c = w4[2], d = w4[3];
    float s0 = a.x * h[0];  s0 = fmaf(a.y, h[1], s0);  s0 = fmaf(a.z, h[2],  s0);  s0 = fmaf(a.w, h[3],  s0);
    float s1 = b.x * h[4];  s1 = fmaf(b.y, h[5], s1);  s1 = fmaf(b.z, h[6],  s1);  s1 = fmaf(b.w, h[7],  s1);
    float s2 = c.x * h[8];  s2 = fmaf(c.y, h[9], s2);  s2 = fmaf(c.z, h[10], s2);  s2 = fmaf(c.w, h[11], s2);
    float s3 = d.x * h[12]; s3 = fmaf(d.y, h[13], s3); s3 = fmaf(d.z, h[14], s3);  s3 = fmaf(d.w, h[15], s3);
    return (s0 + s1) + (s2 + s3);
}

static __device__ __forceinline__ void ln16ip(float* x, const float* __restrict__ g) {
    float mu = 0.f;
#pragma unroll
    for (int h = 0; h < 16; ++h) mu += x[h];
    mu *= 0.0625f;
    float var = 0.f;
#pragma unroll
    for (int h = 0; h < 16; ++h) { float d = x[h] - mu; var = fmaf(d, d, var); }
    var *= 0.0625f;
    const float s = rsqrtf(var + 1e-5f);
#pragma unroll
    for (int h = 0; h < 16; ++h) x[h] = (x[h] - mu) * s * g[h];
}

// radial MLP layers 1+2 (incl. both LayerNorms). w = blob base for this pair.
template <int C>
static __device__ __forceinline__ void radial16(float dist, const float* __restrict__ w, float* hh) {
    float t[16];
#pragma unroll
    for (int h = 0; h < 16; ++h) t[h] = fsilu(fmaf(dist, w[h], w[16 + h]));
    ln16ip(t, w + 32);
    const float* w2t = w + 80 + C;
#pragma unroll
    for (int e = 0; e < 16; ++e) hh[e] = fsilu(w[48 + e] + dot16(w2t + e * 16, t));
    ln16ip(hh, w + 64);
}

// ---------------------------------------------------------------------------
__global__ __launch_bounds__(256) void k_lin_in(
    const float* __restrict__ x0, const float* __restrict__ x1,
    const float* __restrict__ wxi0, const float* __restrict__ wxj0,
    const float* __restrict__ wxi1, const float* __restrict__ wxj1,
    float* __restrict__ xi0, float* __restrict__ xj0,
    float* __restrict__ xi1, float* __restrict__ xj1) {
    const int t = blockIdx.x * 256 + threadIdx.x;  // 131072 threads
    const int n = t >> 4, e = t & 15;
    const float* xr = x0 + n * 16;
    float si = 0.f, sj = 0.f;
#pragma unroll
    for (int d = 0; d < 16; ++d) {
        const float xv = xr[d];
        si = fmaf(xv, wxi0[d * 16 + e], si);
        sj = fmaf(xv, wxj0[d * 16 + e], sj);
    }
    xi0[t] = si; xj0[t] = sj;
    if (e < 8) {
        const float* x1r = x1 + n * 24;
#pragma unroll
        for (int m = 0; m < 3; ++m) {
            float a = 0.f, b = 0.f;
#pragma unroll
            for (int d = 0; d < 8; ++d) {
                const float xv = x1r[d * 3 + m];
                a = fmaf(xv, wxi1[d * 8 + e], a);
                b = fmaf(xv, wxj1[d * 8 + e], b);
            }
            xi1[n * 24 + e * 3 + m] = a;
            xj1[n * 24 + e * 3 + m] = b;
        }
    }
}

// ---------------------------------------------------------------------------
struct RPtrs { const float* a[32]; };  // 4 pairs x (w1,b1,g1,w2,b2,g2,w3,b3)

__global__ void k_wts(RPtrs rp, const unsigned char* __restrict__ maskb,
                      float* __restrict__ wts, int* __restrict__ flagp) {
    const int tid = threadIdx.x;
    const int Cs[4]  = {128, 64, 64, 96};
    const int bas[4] = {BASE00, BASE10, BASE01, BASE11};
#pragma unroll
    for (int pp = 0; pp < 4; ++pp) {
        const int C = Cs[pp];
        float* dst = wts + bas[pp];
        const float* w1 = rp.a[pp * 8 + 0]; const float* b1 = rp.a[pp * 8 + 1];
        const float* g1 = rp.a[pp * 8 + 2]; const float* w2 = rp.a[pp * 8 + 3];
        const float* b2 = rp.a[pp * 8 + 4]; const float* g2 = rp.a[pp * 8 + 5];
        const float* w3 = rp.a[pp * 8 + 6]; const float* b3 = rp.a[pp * 8 + 7];
        if (tid < 16) {
            dst[tid] = w1[tid]; dst[16 + tid] = b1[tid]; dst[32 + tid] = g1[tid];
            dst[48 + tid] = b2[tid]; dst[64 + tid] = g2[tid];
        }
        for (int i = tid; i < C; i += 256) dst[80 + i] = b3[i];
        { const int e = tid >> 4, h = tid & 15; dst[80 + C + tid] = w2[h * 16 + e]; }
        for (int i = tid; i < 16 * C; i += 256) {
            const int c = i >> 4, h = i & 15;
            dst[336 + C + i] = w3[h * C + c];   // w3t[c][h]
        }
    }
    if (tid == 0) {
        // layout detect: int32 {0,1} has all bytes at (i&3)!=0 equal to 0;
        // random bools do not (P(miss) ~ 2^-48).
        int nz = 0;
        for (int i = 1; i < 64; ++i) if (i & 3) nz |= (int)maskb[i];
        *flagp = (nz != 0) ? 1 : 0;
    }
}

// ---------------------------------------------------------------------------
__global__ __launch_bounds__(256) void k_pairs(
    const float* __restrict__ rel,
    const float* __restrict__ b00, const float* __restrict__ b10,
    const float* __restrict__ b01, const float* __restrict__ b11,
    const int* __restrict__ nbr, const unsigned char* __restrict__ maskb,
    const float* __restrict__ xi0, const float* __restrict__ xj0,
    const float* __restrict__ xi1, const float* __restrict__ xj1,
    const float* __restrict__ wts, const int* __restrict__ flagp,
    float* __restrict__ o0, float* __restrict__ o1) {
    const int t = blockIdx.x * 256 + threadIdx.x;  // 262144 threads = (n,k)
    const int n = t >> 5;
    const int j = t;
    const int idx = nbr[j];
    const float dist = rel[j];
    const int bytelay = *flagp;
    const int mv = bytelay ? (int)maskb[j] : ((const int*)maskb)[j];

    // xg for di=0: [16], di=1: [8][3]
    float xg0[16];
    {
        const float4* a = (const float4*)(xj0 + idx * 16);
        const float4* b = (const float4*)(xi0 + n * 16);
#pragma unroll
        for (int q = 0; q < 4; ++q) {
            const float4 u = a[q], v = b[q];
            xg0[4 * q + 0] = u.x + v.x; xg0[4 * q + 1] = u.y + v.y;
            xg0[4 * q + 2] = u.z + v.z; xg0[4 * q + 3] = u.w + v.w;
        }
    }
    float xg1[8][3];
    {
        const float4* a = (const float4*)(xj1 + idx * 24);
        const float4* b = (const float4*)(xi1 + n * 24);
        float tmp[24];
#pragma unroll
        for (int q = 0; q < 6; ++q) {
            const float4 u = a[q], v = b[q];
            tmp[4 * q + 0] = u.x + v.x; tmp[4 * q + 1] = u.y + v.y;
            tmp[4 * q + 2] = u.z + v.z; tmp[4 * q + 3] = u.w + v.w;
        }
#pragma unroll
        for (int i = 0; i < 8; ++i)
#pragma unroll
            for (int m = 0; m < 3; ++m) xg1[i][m] = tmp[i * 3 + m];
    }

    float acc0[16];
    float acc1[8][3];
#pragma unroll
    for (int c = 0; c < 16; ++c) acc0[c] = 0.f;
#pragma unroll
    for (int e = 0; e < 8; ++e) { acc1[e][0] = 0.f; acc1[e][1] = 0.f; acc1[e][2] = 0.f; }

    float hh[16];

    // ---- pair '00' : di=0,do=0, ci=16, co=8, nf=1 ----
    radial16<128>(dist, wts + BASE00, hh);
    {
        const float B = b00[j];
        const float* b3  = wts + BASE00 + 80;
        const float* w3t = wts + BASE00 + 336 + 128;
#pragma unroll
        for (int i = 0; i < 16; ++i) {
            const float t0 = B * xg0[i];
#pragma unroll
            for (int o = 0; o < 8; ++o) {
                const int c = o * 16 + i;
                acc0[o] = fmaf(b3[c] + dot16(w3t + c * 16, hh), t0, acc0[o]);
            }
        }
    }
    // ---- pair '10' : di=1,do=0, ci=8, co=8, nf=1 ----
    radial16<64>(dist, wts + BASE10, hh);
    {
        const float* bp = b10 + j * 3;
        const float B0 = bp[0], B1 = bp[1], B2 = bp[2];  // over mi
        const float* b3  = wts + BASE10 + 80;
        const float* w3t = wts + BASE10 + 336 + 64;
#pragma unroll
        for (int i = 0; i < 8; ++i) {
            const float t0 = B0 * xg1[i][0] + B1 * xg1[i][1] + B2 * xg1[i][2];
#pragma unroll
            for (int o = 0; o < 8; ++o) {
                const int c = o * 8 + i;
                acc0[8 + o] = fmaf(b3[c] + dot16(w3t + c * 16, hh), t0, acc0[8 + o]);
            }
        }
    }
    // ---- pair '01' : di=0,do=1, ci=16, co=4, nf=1 ----
    radial16<64>(dist, wts + BASE01, hh);
    {
        const float* bp = b01 + j * 3;
        const float B0 = bp[0], B1 = bp[1], B2 = bp[2];  // over mo
        const float* b3  = wts + BASE01 + 80;
        const float* w3t = wts + BASE01 + 336 + 64;
#pragma unroll
        for (int i = 0; i < 16; ++i) {
            const float x = xg0[i];
            const float t0 = B0 * x, t1 = B1 * x, t2 = B2 * x;
#pragma unroll
            for (int o = 0; o < 4; ++o) {
                const int c = o * 16 + i;
                const float r = b3[c] + dot16(w3t + c * 16, hh);
                acc1[o][0] = fmaf(r, t0, acc1[o][0]);
                acc1[o][1] = fmaf(r, t1, acc1[o][1]);
                acc1[o][2] = fmaf(r, t2, acc1[o][2]);
            }
        }
    }
    // ---- pair '11' : di=1,do=1, ci=8, co=4, nf=3 ----
    radial16<96>(dist, wts + BASE11, hh);
    {
        const float* bp = b11 + (size_t)j * 27;  // [mo][mi][f]
        const float* b3  = wts + BASE11 + 80;
        const float* w3t = wts + BASE11 + 336 + 96;
#pragma unroll
        for (int f = 0; f < 3; ++f) {
            float bb[9];
#pragma unroll
            for (int pq = 0; pq < 9; ++pq) bb[pq] = bp[pq * 3 + f];
#pragma unroll
            for (int i = 0; i < 8; ++i) {
                const float t0 = bb[0] * xg1[i][0] + bb[1] * xg1[i][1] + bb[2] * xg1[i][2];
                const float t1 = bb[3] * xg1[i][0] + bb[4] * xg1[i][1] + bb[5] * xg1[i][2];
                const float t2 = bb[6] * xg1[i][0] + bb[7] * xg1[i][1] + bb[8] * xg1[i][2];
#pragma unroll
                for (int o = 0; o < 4; ++o) {
                    const int c = (o * 8 + i) * 3 + f;
                    const float r = b3[c] + dot16(w3t + c * 16, hh);
                    acc1[4 + o][0] = fmaf(r, t0, acc1[4 + o][0]);
                    acc1[4 + o][1] = fmaf(r, t1, acc1[4 + o][1]);
                    acc1[4 + o][2] = fmaf(r, t2, acc1[4 + o][2]);
                }
            }
        }
    }

    // ---- masked mean over the 32 neighbors of this node ----
    const float mf = mv ? 1.f : 0.f;
    float cnt = mf;
#pragma unroll
    for (int c = 0; c < 16; ++c) acc0[c] *= mf;
#pragma unroll
    for (int e = 0; e < 8; ++e) { acc1[e][0] *= mf; acc1[e][1] *= mf; acc1[e][2] *= mf; }
    // xor-butterfly over 32-lane halves (offsets <=16 never cross halves of the wave)
#pragma unroll
    for (int off = 16; off > 0; off >>= 1) {
        cnt += __shfl_xor(cnt, off);
#pragma unroll
        for (int c = 0; c < 16; ++c) acc0[c] += __shfl_xor(acc0[c], off);
#pragma unroll
        for (int e = 0; e < 8; ++e)
#pragma unroll
            for (int m = 0; m < 3; ++m) acc1[e][m] += __shfl_xor(acc1[e][m], off);
    }
    const float inv = 1.f / fmaxf(cnt, 1.f);
    const int k = t & 31;
    if (k == 0) {
#pragma unroll
        for (int c = 0; c < 16; ++c) o0[n * 16 + c] = acc0[c] * inv;
    } else if (k == 1) {
#pragma unroll
        for (int e = 0; e < 8; ++e)
#pragma unroll
            for (int m = 0; m < 3; ++m) o1[n * 24 + e * 3 + m] = acc1[e][m] * inv;
    }
}

// ---------------------------------------------------------------------------
__global__ __launch_bounds__(256) void k_out(
    const float* __restrict__ x0, const float* __restrict__ x1,
    const float* __restrict__ i0, const float* __restrict__ i1,
    const float* __restrict__ wo0, const float* __restrict__ wo1,
    const float* __restrict__ ws0, const float* __restrict__ ws1,
    float* __restrict__ out) {
    const int t = blockIdx.x * 256 + threadIdx.x;
    if (t < 131072) {
        const int n = t >> 4, e = t & 15;
        float s = 0.f;
#pragma unroll
        for (int d = 0; d < 16; ++d) {
            s = fmaf(i0[n * 16 + d], wo0[d * 16 + e], s);
            s = fmaf(x0[n * 16 + d], ws0[d * 16 + e], s);
        }
        out[t] = s;
    } else if (t < 327680) {
        const int u = t - 131072;
        const int n = u / 24, r2 = u % 24, e = r2 / 3, m = r2 % 3;
        float s = 0.f;
#pragma unroll
        for (int d = 0; d < 8; ++d) {
            s = fmaf(i1[n * 24 + d * 3 + m], wo1[d * 8 + e], s);
            s = fmaf(x1[n * 24 + d * 3 + m], ws1[d * 8 + e], s);
        }
        out[t] = s;
    }
}

// ---------------------------------------------------------------------------
extern "C" void kernel_launch(void* const* d_in, const int* in_sizes, int n_in,
                              void* d_out, int out_size, void* d_ws, size_t ws_size,
                              hipStream_t stream) {
    const float* x0  = (const float*)d_in[0];
    const float* x1  = (const float*)d_in[1];
    const float* rel = (const float*)d_in[2];
    const float* b00 = (const float*)d_in[3];
    const float* b10 = (const float*)d_in[4];
    const float* b01 = (const float*)d_in[5];
    const float* b11 = (const float*)d_in[6];
    const float* wxi0 = (const float*)d_in[7];
    const float* wxi1 = (const float*)d_in[8];
    const float* wxj0 = (const float*)d_in[9];
    const float* wxj1 = (const float*)d_in[10];
    RPtrs rp;
    for (int i = 0; i < 32; ++i) rp.a[i] = (const float*)d_in[11 + i];
    const float* wo0 = (const float*)d_in[43];
    const float* wo1 = (const float*)d_in[44];
    const float* ws0 = (const float*)d_in[45];
    const float* ws1 = (const float*)d_in[46];
    const int* nbr = (const int*)d_in[47];
    const unsigned char* maskb = (const unsigned char*)d_in[48];

    float* ws = (float*)d_ws;
    float* xi0 = ws + XI0_OFF; float* xj0 = ws + XJ0_OFF;
    float* xi1 = ws + XI1_OFF; float* xj1 = ws + XJ1_OFF;
    float* i0  = ws + INT0_OFF; float* i1 = ws + INT1_OFF;
    float* wts = ws + WTS_OFF;
    int* flagp = (int*)(ws + FLAG_OFF);

    hipLaunchKernelGGL(k_lin_in, dim3(512), dim3(256), 0, stream,
                       x0, x1, wxi0, wxj0, wxi1, wxj1, xi0, xj0, xi1, xj1);
    hipLaunchKernelGGL(k_wts, dim3(1), dim3(256), 0, stream, rp, maskb, wts, flagp);
    hipLaunchKernelGGL(k_pairs, dim3(1024), dim3(256), 0, stream,
                       rel, b00, b10, b01, b11, nbr, maskb,
                       xi0, xj0, xi1, xj1, wts, flagp, i0, i1);
    hipLaunchKernelGGL(k_out, dim3(1280), dim3(256), 0, stream,
                       x0, x1, i0, i1, wo0, wo1, ws0, ws1, (float*)d_out);
}

// Round 3
// 439.904 us; speedup vs baseline: 1.2824x; 1.2824x over previous
//
#include <hip/hip_runtime.h>

// ---------------------------------------------------------------------------
// DTP_5377299055222: SE(3)-equivariant conv block, B=1, N=8192, K=32, H=16
// f32 in / f32 out.
// R2 -> R3: k_pairs now stages all radial weights in LDS (broadcast ds_read
// instead of per-lane VMEM), and accumulates in 4 chunks (00,01 share xg0;
// 10,11 share xg1) with immediate per-chunk butterfly+write to cut VGPRs.
// ---------------------------------------------------------------------------

#define NNODE 8192
#define KNBR  32

// workspace float offsets
#define XI0_OFF   0         // 8192*16
#define XJ0_OFF   131072
#define XI1_OFF   262144    // 8192*24
#define XJ1_OFF   458752
#define INT0_OFF  655360    // 8192*16
#define INT1_OFF  786432    // 8192*24
#define WTS_OFF   983040    // 7328 floats
#define FLAG_OFF  990400    // 1 int

// radial weight blob: per pair [w1 16][b1 16][g1 16][b2 16][g2 16][b3 C][w2t 256][w3t 16C]
// pair order 00,10,01,11 ; C = 128,64,64,96 ; bases 0,2512,3936,5360
#define BASE00 0
#define BASE10 2512
#define BASE01 3936
#define BASE11 5360
#define WTS_FLOATS 7328

static __device__ __forceinline__ float fsilu(float x) {
    return x * (1.0f / (1.0f + __expf(-x)));
}

static __device__ __forceinline__ float dot16(const float* __restrict__ w, const float* h) {
    const float4* w4 = (const float4*)w;
    float4 a = w4[0], b = w4[1], c = w4[2], d = w4[3];
    float s0 = a.x * h[0];  s0 = fmaf(a.y, h[1], s0);  s0 = fmaf(a.z, h[2],  s0);  s0 = fmaf(a.w, h[3],  s0);
    float s1 = b.x * h[4];  s1 = fmaf(b.y, h[5], s1);  s1 = fmaf(b.z, h[6],  s1);  s1 = fmaf(b.w, h[7],  s1);
    float s2 = c.x * h[8];  s2 = fmaf(c.y, h[9], s2);  s2 = fmaf(c.z, h[10], s2);  s2 = fmaf(c.w, h[11], s2);
    float s3 = d.x * h[12]; s3 = fmaf(d.y, h[13], s3); s3 = fmaf(d.z, h[14], s3);  s3 = fmaf(d.w, h[15], s3);
    return (s0 + s1) + (s2 + s3);
}

static __device__ __forceinline__ void ln16ip(float* x, const float* __restrict__ g) {
    float mu = 0.f;
#pragma unroll
    for (int h = 0; h < 16; ++h) mu += x[h];
    mu *= 0.0625f;
    float var = 0.f;
#pragma unroll
    for (int h = 0; h < 16; ++h) { float d = x[h] - mu; var = fmaf(d, d, var); }
    var *= 0.0625f;
    const float s = rsqrtf(var + 1e-5f);
#pragma unroll
    for (int h = 0; h < 16; ++h) x[h] = (x[h] - mu) * s * g[h];
}

// radial MLP layers 1+2 (incl. both LayerNorms). w = blob base (LDS).
template <int C>
static __device__ __forceinline__ void radial16(float dist, const float* __restrict__ w, float* hh) {
    float t[16];
#pragma unroll
    for (int h = 0; h < 16; ++h) t[h] = fsilu(fmaf(dist, w[h], w[16 + h]));
    ln16ip(t, w + 32);
    const float* w2t = w + 80 + C;
#pragma unroll
    for (int e = 0; e < 16; ++e) hh[e] = fsilu(w[48 + e] + dot16(w2t + e * 16, t));
    ln16ip(hh, w + 64);
}

// ---------------------------------------------------------------------------
__global__ __launch_bounds__(256) void k_lin_in(
    const float* __restrict__ x0, const float* __restrict__ x1,
    const float* __restrict__ wxi0, const float* __restrict__ wxj0,
    const float* __restrict__ wxi1, const float* __restrict__ wxj1,
    float* __restrict__ xi0, float* __restrict__ xj0,
    float* __restrict__ xi1, float* __restrict__ xj1) {
    const int t = blockIdx.x * 256 + threadIdx.x;  // 131072 threads
    const int n = t >> 4, e = t & 15;
    const float* xr = x0 + n * 16;
    float si = 0.f, sj = 0.f;
#pragma unroll
    for (int d = 0; d < 16; ++d) {
        const float xv = xr[d];
        si = fmaf(xv, wxi0[d * 16 + e], si);
        sj = fmaf(xv, wxj0[d * 16 + e], sj);
    }
    xi0[t] = si; xj0[t] = sj;
    if (e < 8) {
        const float* x1r = x1 + n * 24;
#pragma unroll
        for (int m = 0; m < 3; ++m) {
            float a = 0.f, b = 0.f;
#pragma unroll
            for (int d = 0; d < 8; ++d) {
                const float xv = x1r[d * 3 + m];
                a = fmaf(xv, wxi1[d * 8 + e], a);
                b = fmaf(xv, wxj1[d * 8 + e], b);
            }
            xi1[n * 24 + e * 3 + m] = a;
            xj1[n * 24 + e * 3 + m] = b;
        }
    }
}

// ---------------------------------------------------------------------------
struct RPtrs { const float* a[32]; };  // 4 pairs x (w1,b1,g1,w2,b2,g2,w3,b3)

__global__ void k_wts(RPtrs rp, const unsigned char* __restrict__ maskb,
                      float* __restrict__ wts, int* __restrict__ flagp) {
    const int tid = threadIdx.x;
    const int Cs[4]  = {128, 64, 64, 96};
    const int bas[4] = {BASE00, BASE10, BASE01, BASE11};
#pragma unroll
    for (int pp = 0; pp < 4; ++pp) {
        const int C = Cs[pp];
        float* dst = wts + bas[pp];
        const float* w1 = rp.a[pp * 8 + 0]; const float* b1 = rp.a[pp * 8 + 1];
        const float* g1 = rp.a[pp * 8 + 2]; const float* w2 = rp.a[pp * 8 + 3];
        const float* b2 = rp.a[pp * 8 + 4]; const float* g2 = rp.a[pp * 8 + 5];
        const float* w3 = rp.a[pp * 8 + 6]; const float* b3 = rp.a[pp * 8 + 7];
        if (tid < 16) {
            dst[tid] = w1[tid]; dst[16 + tid] = b1[tid]; dst[32 + tid] = g1[tid];
            dst[48 + tid] = b2[tid]; dst[64 + tid] = g2[tid];
        }
        for (int i = tid; i < C; i += 256) dst[80 + i] = b3[i];
        { const int e = tid >> 4, h = tid & 15; dst[80 + C + tid] = w2[h * 16 + e]; }
        for (int i = tid; i < 16 * C; i += 256) {
            const int c = i >> 4, h = i & 15;
            dst[336 + C + i] = w3[h * C + c];   // w3t[c][h]
        }
    }
    if (tid == 0) {
        // layout detect: int32 {0,1} has all bytes at (i&3)!=0 equal to 0;
        // random bools do not (P(miss) ~ 2^-48).
        int nz = 0;
        for (int i = 1; i < 64; ++i) if (i & 3) nz |= (int)maskb[i];
        *flagp = (nz != 0) ? 1 : 0;
    }
}

// ---------------------------------------------------------------------------
// One thread per (n,k). All radial weights live in LDS (broadcast reads).
// Accumulate in 4 chunks; butterfly-reduce + write each chunk immediately to
// keep register pressure low (target <=128 VGPR -> 4 blocks/CU).
__global__ __launch_bounds__(256, 4) void k_pairs2(
    const float* __restrict__ rel,
    const float* __restrict__ b00, const float* __restrict__ b10,
    const float* __restrict__ b01, const float* __restrict__ b11,
    const int* __restrict__ nbr, const unsigned char* __restrict__ maskb,
    const float* __restrict__ xi0, const float* __restrict__ xj0,
    const float* __restrict__ xi1, const float* __restrict__ xj1,
    const float* __restrict__ wts, const int* __restrict__ flagp,
    float* __restrict__ o0, float* __restrict__ o1) {
    __shared__ float4 sw4[WTS_FLOATS / 4];

    const int t = blockIdx.x * 256 + threadIdx.x;  // 262144 threads = (n,k)
    const int n = t >> 5;
    const int k = t & 31;
    const int j = t;

    // issue per-thread scalar loads before the staging barrier (hide latency)
    const int idx = nbr[j];
    const float dist = rel[j];
    const int bytelay = *flagp;
    const int mv = bytelay ? (int)maskb[j] : ((const int*)maskb)[j];

    // stage weight blob into LDS
    {
        const float4* g4 = (const float4*)wts;
        for (int i = threadIdx.x; i < WTS_FLOATS / 4; i += 256) sw4[i] = g4[i];
    }
    __syncthreads();
    const float* sw = (const float*)sw4;

    const float mf = mv ? 1.f : 0.f;
    float cnt = mf;
#pragma unroll
    for (int off = 16; off > 0; off >>= 1) cnt += __shfl_xor(cnt, off);
    const float inv = 1.f / fmaxf(cnt, 1.f);

    float hh[16];

    // ---- xg0 (masked) ----
    float xg0[16];
    {
        const float4* a = (const float4*)(xj0 + idx * 16);
        const float4* b = (const float4*)(xi0 + n * 16);
#pragma unroll
        for (int q = 0; q < 4; ++q) {
            const float4 u = a[q], v = b[q];
            xg0[4 * q + 0] = (u.x + v.x) * mf; xg0[4 * q + 1] = (u.y + v.y) * mf;
            xg0[4 * q + 2] = (u.z + v.z) * mf; xg0[4 * q + 3] = (u.w + v.w) * mf;
        }
    }

    // ---- pair '00' : di=0,do=0, ci=16, co=8, nf=1 -> o0[0..7] ----
    radial16<128>(dist, sw + BASE00, hh);
    {
        const float Bv = b00[j];
        const float* b3  = sw + BASE00 + 80;
        const float* w3t = sw + BASE00 + 336 + 128;
        float acc[8];
#pragma unroll
        for (int o = 0; o < 8; ++o) acc[o] = 0.f;
#pragma unroll
        for (int i = 0; i < 16; ++i) {
            const float t0 = Bv * xg0[i];
#pragma unroll
            for (int o = 0; o < 8; ++o) {
                const int c = o * 16 + i;
                acc[o] = fmaf(b3[c] + dot16(w3t + c * 16, hh), t0, acc[o]);
            }
        }
#pragma unroll
        for (int off = 16; off > 0; off >>= 1)
#pragma unroll
            for (int o = 0; o < 8; ++o) acc[o] += __shfl_xor(acc[o], off);
        if (k == 0) {
#pragma unroll
            for (int o = 0; o < 8; ++o) o0[n * 16 + o] = acc[o] * inv;
        }
    }

    // ---- pair '01' : di=0,do=1, ci=16, co=4, nf=1 -> o1[e=0..3] ----
    radial16<64>(dist, sw + BASE01, hh);
    {
        const float* bp = b01 + j * 3;
        const float B0 = bp[0], B1 = bp[1], B2 = bp[2];  // over mo
        const float* b3  = sw + BASE01 + 80;
        const float* w3t = sw + BASE01 + 336 + 64;
        float a1[4][3];
#pragma unroll
        for (int o = 0; o < 4; ++o) { a1[o][0] = 0.f; a1[o][1] = 0.f; a1[o][2] = 0.f; }
#pragma unroll
        for (int i = 0; i < 16; ++i) {
            const float x = xg0[i];
            const float t0 = B0 * x, t1 = B1 * x, t2 = B2 * x;
#pragma unroll
            for (int o = 0; o < 4; ++o) {
                const int c = o * 16 + i;
                const float r = b3[c] + dot16(w3t + c * 16, hh);
                a1[o][0] = fmaf(r, t0, a1[o][0]);
                a1[o][1] = fmaf(r, t1, a1[o][1]);
                a1[o][2] = fmaf(r, t2, a1[o][2]);
            }
        }
#pragma unroll
        for (int off = 16; off > 0; off >>= 1)
#pragma unroll
            for (int o = 0; o < 4; ++o)
#pragma unroll
                for (int m = 0; m < 3; ++m) a1[o][m] += __shfl_xor(a1[o][m], off);
        if (k == 1) {
#pragma unroll
            for (int o = 0; o < 4; ++o)
#pragma unroll
                for (int m = 0; m < 3; ++m) o1[n * 24 + o * 3 + m] = a1[o][m] * inv;
        }
    }

    // ---- xg1 (masked) ----
    float xg1[8][3];
    {
        const float4* a = (const float4*)(xj1 + idx * 24);
        const float4* b = (const float4*)(xi1 + n * 24);
        float tmp[24];
#pragma unroll
        for (int q = 0; q < 6; ++q) {
            const float4 u = a[q], v = b[q];
            tmp[4 * q + 0] = (u.x + v.x) * mf; tmp[4 * q + 1] = (u.y + v.y) * mf;
            tmp[4 * q + 2] = (u.z + v.z) * mf; tmp[4 * q + 3] = (u.w + v.w) * mf;
        }
#pragma unroll
        for (int i = 0; i < 8; ++i)
#pragma unroll
            for (int m = 0; m < 3; ++m) xg1[i][m] = tmp[i * 3 + m];
    }

    // ---- pair '10' : di=1,do=0, ci=8, co=8, nf=1 -> o0[8..15] ----
    radial16<64>(dist, sw + BASE10, hh);
    {
        const float* bp = b10 + j * 3;
        const float B0 = bp[0], B1 = bp[1], B2 = bp[2];  // over mi
        const float* b3  = sw + BASE10 + 80;
        const float* w3t = sw + BASE10 + 336 + 64;
        float acc[8];
#pragma unroll
        for (int o = 0; o < 8; ++o) acc[o] = 0.f;
#pragma unroll
        for (int i = 0; i < 8; ++i) {
            const float t0 = B0 * xg1[i][0] + B1 * xg1[i][1] + B2 * xg1[i][2];
#pragma unroll
            for (int o = 0; o < 8; ++o) {
                const int c = o * 8 + i;
                acc[o] = fmaf(b3[c] + dot16(w3t + c * 16, hh), t0, acc[o]);
            }
        }
#pragma unroll
        for (int off = 16; off > 0; off >>= 1)
#pragma unroll
            for (int o = 0; o < 8; ++o) acc[o] += __shfl_xor(acc[o], off);
        if (k == 0) {
#pragma unroll
            for (int o = 0; o < 8; ++o) o0[n * 16 + 8 + o] = acc[o] * inv;
        }
    }

    // ---- pair '11' : di=1,do=1, ci=8, co=4, nf=3 -> o1[e=4..7] ----
    radial16<96>(dist, sw + BASE11, hh);
    {
        const float* bp = b11 + (size_t)j * 27;  // [mo][mi][f]
        const float* b3  = sw + BASE11 + 80;
        const float* w3t = sw + BASE11 + 336 + 96;
        float a1[4][3];
#pragma unroll
        for (int o = 0; o < 4; ++o) { a1[o][0] = 0.f; a1[o][1] = 0.f; a1[o][2] = 0.f; }
#pragma unroll
        for (int f = 0; f < 3; ++f) {
            float bb[9];
#pragma unroll
            for (int pq = 0; pq < 9; ++pq) bb[pq] = bp[pq * 3 + f];
#pragma unroll
            for (int i = 0; i < 8; ++i) {
                const float t0 = bb[0] * xg1[i][0] + bb[1] * xg1[i][1] + bb[2] * xg1[i][2];
                const float t1 = bb[3] * xg1[i][0] + bb[4] * xg1[i][1] + bb[5] * xg1[i][2];
                const float t2 = bb[6] * xg1[i][0] + bb[7] * xg1[i][1] + bb[8] * xg1[i][2];
#pragma unroll
                for (int o = 0; o < 4; ++o) {
                    const int c = (o * 8 + i) * 3 + f;
                    const float r = b3[c] + dot16(w3t + c * 16, hh);
                    a1[o][0] = fmaf(r, t0, a1[o][0]);
                    a1[o][1] = fmaf(r, t1, a1[o][1]);
                    a1[o][2] = fmaf(r, t2, a1[o][2]);
                }
            }
        }
#pragma unroll
        for (int off = 16; off > 0; off >>= 1)
#pragma unroll
            for (int o = 0; o < 4; ++o)
#pragma unroll
                for (int m = 0; m < 3; ++m) a1[o][m] += __shfl_xor(a1[o][m], off);
        if (k == 1) {
#pragma unroll
            for (int o = 0; o < 4; ++o)
#pragma unroll
                for (int m = 0; m < 3; ++m) o1[n * 24 + (4 + o) * 3 + m] = a1[o][m] * inv;
        }
    }
}

// ---------------------------------------------------------------------------
__global__ __launch_bounds__(256) void k_out(
    const float* __restrict__ x0, const float* __restrict__ x1,
    const float* __restrict__ i0, const float* __restrict__ i1,
    const float* __restrict__ wo0, const float* __restrict__ wo1,
    const float* __restrict__ ws0, const float* __restrict__ ws1,
    float* __restrict__ out) {
    const int t = blockIdx.x * 256 + threadIdx.x;
    if (t < 131072) {
        const int n = t >> 4, e = t & 15;
        float s = 0.f;
#pragma unroll
        for (int d = 0; d < 16; ++d) {
            s = fmaf(i0[n * 16 + d], wo0[d * 16 + e], s);
            s = fmaf(x0[n * 16 + d], ws0[d * 16 + e], s);
        }
        out[t] = s;
    } else if (t < 327680) {
        const int u = t - 131072;
        const int n = u / 24, r2 = u % 24, e = r2 / 3, m = r2 % 3;
        float s = 0.f;
#pragma unroll
        for (int d = 0; d < 8; ++d) {
            s = fmaf(i1[n * 24 + d * 3 + m], wo1[d * 8 + e], s);
            s = fmaf(x1[n * 24 + d * 3 + m], ws1[d * 8 + e], s);
        }
        out[t] = s;
    }
}

// ---------------------------------------------------------------------------
extern "C" void kernel_launch(void* const* d_in, const int* in_sizes, int n_in,
                              void* d_out, int out_size, void* d_ws, size_t ws_size,
                              hipStream_t stream) {
    const float* x0  = (const float*)d_in[0];
    const float* x1  = (const float*)d_in[1];
    const float* rel = (const float*)d_in[2];
    const float* b00 = (const float*)d_in[3];
    const float* b10 = (const float*)d_in[4];
    const float* b01 = (const float*)d_in[5];
    const float* b11 = (const float*)d_in[6];
    const float* wxi0 = (const float*)d_in[7];
    const float* wxi1 = (const float*)d_in[8];
    const float* wxj0 = (const float*)d_in[9];
    const float* wxj1 = (const float*)d_in[10];
    RPtrs rp;
    for (int i = 0; i < 32; ++i) rp.a[i] = (const float*)d_in[11 + i];
    const float* wo0 = (const float*)d_in[43];
    const float* wo1 = (const float*)d_in[44];
    const float* ws0 = (const float*)d_in[45];
    const float* ws1 = (const float*)d_in[46];
    const int* nbr = (const int*)d_in[47];
    const unsigned char* maskb = (const unsigned char*)d_in[48];

    float* ws = (float*)d_ws;
    float* xi0 = ws + XI0_OFF; float* xj0 = ws + XJ0_OFF;
    float* xi1 = ws + XI1_OFF; float* xj1 = ws + XJ1_OFF;
    float* i0  = ws + INT0_OFF; float* i1 = ws + INT1_OFF;
    float* wts = ws + WTS_OFF;
    int* flagp = (int*)(ws + FLAG_OFF);

    hipLaunchKernelGGL(k_lin_in, dim3(512), dim3(256), 0, stream,
                       x0, x1, wxi0, wxj0, wxi1, wxj1, xi0, xj0, xi1, xj1);
    hipLaunchKernelGGL(k_wts, dim3(1), dim3(256), 0, stream, rp, maskb, wts, flagp);
    hipLaunchKernelGGL(k_pairs2, dim3(1024), dim3(256), 0, stream,
                       rel, b00, b10, b01, b11, nbr, maskb,
                       xi0, xj0, xi1, xj1, wts, flagp, i0, i1);
    hipLaunchKernelGGL(k_out, dim3(1280), dim3(256), 0, stream,
                       x0, x1, i0, i1, wo0, wo1, ws0, ws1, (float*)d_out);
}

// Round 4
// 344.398 us; speedup vs baseline: 1.6380x; 1.2773x over previous
//
#include <hip/hip_runtime.h>

// ---------------------------------------------------------------------------
// DTP_5377299055222: SE(3)-equivariant conv block, B=1, N=8192, K=32, H=16
// f32 in / f32 out.
// R3 -> R4: k_pairs split into k_pairsA (pairs 00,01 over xg0) and k_pairsB
// (pairs 10,11 over xg1) to cut per-thread live registers (~80) so no scratch
// spills (R3: 790 MB spill writes = the whole runtime). Weight blob reordered
// (00,01,10,11) so each kernel LDS-stages a contiguous half (~15 KB).
// launch_bounds(256,3): VGPR cap ~170 >> demand -> no spill cascade.
// ---------------------------------------------------------------------------

#define NNODE 8192
#define KNBR  32

// workspace float offsets
#define XI0_OFF   0         // 8192*16
#define XJ0_OFF   131072
#define XI1_OFF   262144    // 8192*24
#define XJ1_OFF   458752
#define INT0_OFF  655360    // 8192*16
#define INT1_OFF  786432    // 8192*24
#define WTS_OFF   983040    // 7328 floats
#define FLAG_OFF  990400    // 1 int

// radial weight blob per pair: [w1 16][b1 16][g1 16][b2 16][g2 16][b3 C][w2t 256][w3t 16C]
// = 336 + 17C floats.  Order now 00,01,10,11 ; C = 128,64,64,96.
#define BASE00 0
#define BASE01 2512
#define BASE10 3936
#define BASE11 5360
#define WTS_FLOATS 7328
#define HALF_A 3936         // floats staged by kernel A  (00+01)
#define HALF_B 3392         // floats staged by kernel B  (10+11)

static __device__ __forceinline__ float fsilu(float x) {
    return x * (1.0f / (1.0f + __expf(-x)));
}

static __device__ __forceinline__ float dot16(const float* __restrict__ w, const float* h) {
    const float4* w4 = (const float4*)w;
    float4 a = w4[0], b = w4[1], c = w4[2], d = w4[3];
    float s0 = a.x * h[0];  s0 = fmaf(a.y, h[1], s0);  s0 = fmaf(a.z, h[2],  s0);  s0 = fmaf(a.w, h[3],  s0);
    float s1 = b.x * h[4];  s1 = fmaf(b.y, h[5], s1);  s1 = fmaf(b.z, h[6],  s1);  s1 = fmaf(b.w, h[7],  s1);
    float s2 = c.x * h[8];  s2 = fmaf(c.y, h[9], s2);  s2 = fmaf(c.z, h[10], s2);  s2 = fmaf(c.w, h[11], s2);
    float s3 = d.x * h[12]; s3 = fmaf(d.y, h[13], s3); s3 = fmaf(d.z, h[14], s3);  s3 = fmaf(d.w, h[15], s3);
    return (s0 + s1) + (s2 + s3);
}

static __device__ __forceinline__ void ln16ip(float* x, const float* __restrict__ g) {
    float mu = 0.f;
#pragma unroll
    for (int h = 0; h < 16; ++h) mu += x[h];
    mu *= 0.0625f;
    float var = 0.f;
#pragma unroll
    for (int h = 0; h < 16; ++h) { float d = x[h] - mu; var = fmaf(d, d, var); }
    var *= 0.0625f;
    const float s = rsqrtf(var + 1e-5f);
#pragma unroll
    for (int h = 0; h < 16; ++h) x[h] = (x[h] - mu) * s * g[h];
}

// radial MLP layers 1+2 (incl. both LayerNorms). w = blob base (LDS).
template <int C>
static __device__ __forceinline__ void radial16(float dist, const float* __restrict__ w, float* hh) {
    float t[16];
#pragma unroll
    for (int h = 0; h < 16; ++h) t[h] = fsilu(fmaf(dist, w[h], w[16 + h]));
    ln16ip(t, w + 32);
    const float* w2t = w + 80 + C;
#pragma unroll
    for (int e = 0; e < 16; ++e) hh[e] = fsilu(w[48 + e] + dot16(w2t + e * 16, t));
    ln16ip(hh, w + 64);
}

// ---------------------------------------------------------------------------
__global__ __launch_bounds__(256) void k_lin_in(
    const float* __restrict__ x0, const float* __restrict__ x1,
    const float* __restrict__ wxi0, const float* __restrict__ wxj0,
    const float* __restrict__ wxi1, const float* __restrict__ wxj1,
    float* __restrict__ xi0, float* __restrict__ xj0,
    float* __restrict__ xi1, float* __restrict__ xj1) {
    const int t = blockIdx.x * 256 + threadIdx.x;  // 131072 threads
    const int n = t >> 4, e = t & 15;
    const float* xr = x0 + n * 16;
    float si = 0.f, sj = 0.f;
#pragma unroll
    for (int d = 0; d < 16; ++d) {
        const float xv = xr[d];
        si = fmaf(xv, wxi0[d * 16 + e], si);
        sj = fmaf(xv, wxj0[d * 16 + e], sj);
    }
    xi0[t] = si; xj0[t] = sj;
    if (e < 8) {
        const float* x1r = x1 + n * 24;
#pragma unroll
        for (int m = 0; m < 3; ++m) {
            float a = 0.f, b = 0.f;
#pragma unroll
            for (int d = 0; d < 8; ++d) {
                const float xv = x1r[d * 3 + m];
                a = fmaf(xv, wxi1[d * 8 + e], a);
                b = fmaf(xv, wxj1[d * 8 + e], b);
            }
            xi1[n * 24 + e * 3 + m] = a;
            xj1[n * 24 + e * 3 + m] = b;
        }
    }
}

// ---------------------------------------------------------------------------
struct RPtrs { const float* a[32]; };  // input order: 00,10,01,11 x (w1,b1,g1,w2,b2,g2,w3,b3)

__global__ void k_wts(RPtrs rp, const unsigned char* __restrict__ maskb,
                      float* __restrict__ wts, int* __restrict__ flagp) {
    const int tid = threadIdx.x;
    const int Cs[4]  = {128, 64, 64, 96};                 // blob order 00,01,10,11
    const int bas[4] = {BASE00, BASE01, BASE10, BASE11};
    const int rpi[4] = {0, 2, 1, 3};                      // d_in group for each blob slot
#pragma unroll
    for (int pp = 0; pp < 4; ++pp) {
        const int C = Cs[pp];
        float* dst = wts + bas[pp];
        const float* w1 = rp.a[rpi[pp] * 8 + 0]; const float* b1 = rp.a[rpi[pp] * 8 + 1];
        const float* g1 = rp.a[rpi[pp] * 8 + 2]; const float* w2 = rp.a[rpi[pp] * 8 + 3];
        const float* b2 = rp.a[rpi[pp] * 8 + 4]; const float* g2 = rp.a[rpi[pp] * 8 + 5];
        const float* w3 = rp.a[rpi[pp] * 8 + 6]; const float* b3 = rp.a[rpi[pp] * 8 + 7];
        if (tid < 16) {
            dst[tid] = w1[tid]; dst[16 + tid] = b1[tid]; dst[32 + tid] = g1[tid];
            dst[48 + tid] = b2[tid]; dst[64 + tid] = g2[tid];
        }
        for (int i = tid; i < C; i += 256) dst[80 + i] = b3[i];
        { const int e = tid >> 4, h = tid & 15; dst[80 + C + tid] = w2[h * 16 + e]; }
        for (int i = tid; i < 16 * C; i += 256) {
            const int c = i >> 4, h = i & 15;
            dst[336 + C + i] = w3[h * C + c];   // w3t[c][h]
        }
    }
    if (tid == 0) {
        // layout detect: int32 {0,1} has all bytes at (i&3)!=0 equal to 0;
        // random bools do not (P(miss) ~ 2^-48).
        int nz = 0;
        for (int i = 1; i < 64; ++i) if (i & 3) nz |= (int)maskb[i];
        *flagp = (nz != 0) ? 1 : 0;
    }
}

// ---------------------------------------------------------------------------
// Kernel A: pairs 00 (ci16,co8,nf1) and 01 (ci16,co4,nf1). One thread/(n,k).
__global__ __launch_bounds__(256, 3) void k_pairsA(
    const float* __restrict__ rel,
    const float* __restrict__ b00, const float* __restrict__ b01,
    const int* __restrict__ nbr, const unsigned char* __restrict__ maskb,
    const float* __restrict__ xi0, const float* __restrict__ xj0,
    const float* __restrict__ wts, const int* __restrict__ flagp,
    float* __restrict__ o0, float* __restrict__ o1) {
    __shared__ float4 sw4[HALF_A / 4];

    const int t = blockIdx.x * 256 + threadIdx.x;
    const int n = t >> 5;
    const int k = t & 31;
    const int j = t;

    const int idx = nbr[j];
    const float dist = rel[j];
    const int bytelay = *flagp;
    const int mv = bytelay ? (int)maskb[j] : ((const int*)maskb)[j];

    {
        const float4* g4 = (const float4*)wts;
        for (int i = threadIdx.x; i < HALF_A / 4; i += 256) sw4[i] = g4[i];
    }
    __syncthreads();
    const float* sw = (const float*)sw4;

    const float mf = mv ? 1.f : 0.f;
    float cnt = mf;
#pragma unroll
    for (int off = 16; off > 0; off >>= 1) cnt += __shfl_xor(cnt, off);
    const float inv = 1.f / fmaxf(cnt, 1.f);

    float xg0[16];
    {
        const float4* a = (const float4*)(xj0 + idx * 16);
        const float4* b = (const float4*)(xi0 + n * 16);
#pragma unroll
        for (int q = 0; q < 4; ++q) {
            const float4 u = a[q], v = b[q];
            xg0[4 * q + 0] = (u.x + v.x) * mf; xg0[4 * q + 1] = (u.y + v.y) * mf;
            xg0[4 * q + 2] = (u.z + v.z) * mf; xg0[4 * q + 3] = (u.w + v.w) * mf;
        }
    }

    float hh[16];

    // ---- pair '00' -> o0[0..7] ----
    radial16<128>(dist, sw + BASE00, hh);
    {
        const float Bv = b00[j];
        const float* b3  = sw + BASE00 + 80;
        const float* w3t = sw + BASE00 + 336 + 128;
        float acc[8];
#pragma unroll
        for (int o = 0; o < 8; ++o) acc[o] = 0.f;
#pragma unroll
        for (int i = 0; i < 16; ++i) {
            const float t0 = Bv * xg0[i];
#pragma unroll
            for (int o = 0; o < 8; ++o) {
                const int c = o * 16 + i;
                acc[o] = fmaf(b3[c] + dot16(w3t + c * 16, hh), t0, acc[o]);
            }
        }
#pragma unroll
        for (int off = 16; off > 0; off >>= 1)
#pragma unroll
            for (int o = 0; o < 8; ++o) acc[o] += __shfl_xor(acc[o], off);
        if (k == 0) {
#pragma unroll
            for (int o = 0; o < 8; ++o) o0[n * 16 + o] = acc[o] * inv;
        }
    }

    // ---- pair '01' -> o1[e=0..3] ----
    radial16<64>(dist, sw + BASE01, hh);
    {
        const float* bp = b01 + j * 3;
        const float B0 = bp[0], B1 = bp[1], B2 = bp[2];  // over mo
        const float* b3  = sw + BASE01 + 80;
        const float* w3t = sw + BASE01 + 336 + 64;
        float a1[4][3];
#pragma unroll
        for (int o = 0; o < 4; ++o) { a1[o][0] = 0.f; a1[o][1] = 0.f; a1[o][2] = 0.f; }
#pragma unroll
        for (int i = 0; i < 16; ++i) {
            const float x = xg0[i];
            const float t0 = B0 * x, t1 = B1 * x, t2 = B2 * x;
#pragma unroll
            for (int o = 0; o < 4; ++o) {
                const int c = o * 16 + i;
                const float r = b3[c] + dot16(w3t + c * 16, hh);
                a1[o][0] = fmaf(r, t0, a1[o][0]);
                a1[o][1] = fmaf(r, t1, a1[o][1]);
                a1[o][2] = fmaf(r, t2, a1[o][2]);
            }
        }
#pragma unroll
        for (int off = 16; off > 0; off >>= 1)
#pragma unroll
            for (int o = 0; o < 4; ++o)
#pragma unroll
                for (int m = 0; m < 3; ++m) a1[o][m] += __shfl_xor(a1[o][m], off);
        if (k == 1) {
#pragma unroll
            for (int o = 0; o < 4; ++o)
#pragma unroll
                for (int m = 0; m < 3; ++m) o1[n * 24 + o * 3 + m] = a1[o][m] * inv;
        }
    }
}

// ---------------------------------------------------------------------------
// Kernel B: pairs 10 (ci8,co8,nf1) and 11 (ci8,co4,nf3). One thread/(n,k).
__global__ __launch_bounds__(256, 3) void k_pairsB(
    const float* __restrict__ rel,
    const float* __restrict__ b10, const float* __restrict__ b11,
    const int* __restrict__ nbr, const unsigned char* __restrict__ maskb,
    const float* __restrict__ xi1, const float* __restrict__ xj1,
    const float* __restrict__ wts, const int* __restrict__ flagp,
    float* __restrict__ o0, float* __restrict__ o1) {
    __shared__ float4 sw4[HALF_B / 4];

    const int t = blockIdx.x * 256 + threadIdx.x;
    const int n = t >> 5;
    const int k = t & 31;
    const int j = t;

    const int idx = nbr[j];
    const float dist = rel[j];
    const int bytelay = *flagp;
    const int mv = bytelay ? (int)maskb[j] : ((const int*)maskb)[j];

    {
        const float4* g4 = (const float4*)(wts + HALF_A);
        for (int i = threadIdx.x; i < HALF_B / 4; i += 256) sw4[i] = g4[i];
    }
    __syncthreads();
    const float* sw = (const float*)sw4;
    // LDS-local bases: '10' at 0, '11' at 1424
    const int L10 = 0, L11 = BASE11 - BASE10;

    const float mf = mv ? 1.f : 0.f;
    float cnt = mf;
#pragma unroll
    for (int off = 16; off > 0; off >>= 1) cnt += __shfl_xor(cnt, off);
    const float inv = 1.f / fmaxf(cnt, 1.f);

    float xg1[8][3];
    {
        const float4* a = (const float4*)(xj1 + idx * 24);
        const float4* b = (const float4*)(xi1 + n * 24);
        float tmp[24];
#pragma unroll
        for (int q = 0; q < 6; ++q) {
            const float4 u = a[q], v = b[q];
            tmp[4 * q + 0] = (u.x + v.x) * mf; tmp[4 * q + 1] = (u.y + v.y) * mf;
            tmp[4 * q + 2] = (u.z + v.z) * mf; tmp[4 * q + 3] = (u.w + v.w) * mf;
        }
#pragma unroll
        for (int i = 0; i < 8; ++i)
#pragma unroll
            for (int m = 0; m < 3; ++m) xg1[i][m] = tmp[i * 3 + m];
    }

    float hh[16];

    // ---- pair '10' -> o0[8..15] ----
    radial16<64>(dist, sw + L10, hh);
    {
        const float* bp = b10 + j * 3;
        const float B0 = bp[0], B1 = bp[1], B2 = bp[2];  // over mi
        const float* b3  = sw + L10 + 80;
        const float* w3t = sw + L10 + 336 + 64;
        float acc[8];
#pragma unroll
        for (int o = 0; o < 8; ++o) acc[o] = 0.f;
#pragma unroll
        for (int i = 0; i < 8; ++i) {
            const float t0 = B0 * xg1[i][0] + B1 * xg1[i][1] + B2 * xg1[i][2];
#pragma unroll
            for (int o = 0; o < 8; ++o) {
                const int c = o * 8 + i;
                acc[o] = fmaf(b3[c] + dot16(w3t + c * 16, hh), t0, acc[o]);
            }
        }
#pragma unroll
        for (int off = 16; off > 0; off >>= 1)
#pragma unroll
            for (int o = 0; o < 8; ++o) acc[o] += __shfl_xor(acc[o], off);
        if (k == 0) {
#pragma unroll
            for (int o = 0; o < 8; ++o) o0[n * 16 + 8 + o] = acc[o] * inv;
        }
    }

    // ---- pair '11' -> o1[e=4..7] ----
    radial16<96>(dist, sw + L11, hh);
    {
        const float* bp = b11 + (size_t)j * 27;  // [mo][mi][f]
        const float* b3  = sw + L11 + 80;
        const float* w3t = sw + L11 + 336 + 96;
        float a1[4][3];
#pragma unroll
        for (int o = 0; o < 4; ++o) { a1[o][0] = 0.f; a1[o][1] = 0.f; a1[o][2] = 0.f; }
#pragma unroll
        for (int f = 0; f < 3; ++f) {
            float bb[9];
#pragma unroll
            for (int pq = 0; pq < 9; ++pq) bb[pq] = bp[pq * 3 + f];
#pragma unroll
            for (int i = 0; i < 8; ++i) {
                const float t0 = bb[0] * xg1[i][0] + bb[1] * xg1[i][1] + bb[2] * xg1[i][2];
                const float t1 = bb[3] * xg1[i][0] + bb[4] * xg1[i][1] + bb[5] * xg1[i][2];
                const float t2 = bb[6] * xg1[i][0] + bb[7] * xg1[i][1] + bb[8] * xg1[i][2];
#pragma unroll
                for (int o = 0; o < 4; ++o) {
                    const int c = (o * 8 + i) * 3 + f;
                    const float r = b3[c] + dot16(w3t + c * 16, hh);
                    a1[o][0] = fmaf(r, t0, a1[o][0]);
                    a1[o][1] = fmaf(r, t1, a1[o][1]);
                    a1[o][2] = fmaf(r, t2, a1[o][2]);
                }
            }
        }
#pragma unroll
        for (int off = 16; off > 0; off >>= 1)
#pragma unroll
            for (int o = 0; o < 4; ++o)
#pragma unroll
                for (int m = 0; m < 3; ++m) a1[o][m] += __shfl_xor(a1[o][m], off);
        if (k == 1) {
#pragma unroll
            for (int o = 0; o < 4; ++o)
#pragma unroll
                for (int m = 0; m < 3; ++m) o1[n * 24 + (4 + o) * 3 + m] = a1[o][m] * inv;
        }
    }
}

// ---------------------------------------------------------------------------
__global__ __launch_bounds__(256) void k_out(
    const float* __restrict__ x0, const float* __restrict__ x1,
    const float* __restrict__ i0, const float* __restrict__ i1,
    const float* __restrict__ wo0, const float* __restrict__ wo1,
    const float* __restrict__ ws0, const float* __restrict__ ws1,
    float* __restrict__ out) {
    const int t = blockIdx.x * 256 + threadIdx.x;
    if (t < 131072) {
        const int n = t >> 4, e = t & 15;
        float s = 0.f;
#pragma unroll
        for (int d = 0; d < 16; ++d) {
            s = fmaf(i0[n * 16 + d], wo0[d * 16 + e], s);
            s = fmaf(x0[n * 16 + d], ws0[d * 16 + e], s);
        }
        out[t] = s;
    } else if (t < 327680) {
        const int u = t - 131072;
        const int n = u / 24, r2 = u % 24, e = r2 / 3, m = r2 % 3;
        float s = 0.f;
#pragma unroll
        for (int d = 0; d < 8; ++d) {
            s = fmaf(i1[n * 24 + d * 3 + m], wo1[d * 8 + e], s);
            s = fmaf(x1[n * 24 + d * 3 + m], ws1[d * 8 + e], s);
        }
        out[t] = s;
    }
}

// ---------------------------------------------------------------------------
extern "C" void kernel_launch(void* const* d_in, const int* in_sizes, int n_in,
                              void* d_out, int out_size, void* d_ws, size_t ws_size,
                              hipStream_t stream) {
    const float* x0  = (const float*)d_in[0];
    const float* x1  = (const float*)d_in[1];
    const float* rel = (const float*)d_in[2];
    const float* b00 = (const float*)d_in[3];
    const float* b10 = (const float*)d_in[4];
    const float* b01 = (const float*)d_in[5];
    const float* b11 = (const float*)d_in[6];
    const float* wxi0 = (const float*)d_in[7];
    const float* wxi1 = (const float*)d_in[8];
    const float* wxj0 = (const float*)d_in[9];
    const float* wxj1 = (const float*)d_in[10];
    RPtrs rp;
    for (int i = 0; i < 32; ++i) rp.a[i] = (const float*)d_in[11 + i];
    const float* wo0 = (const float*)d_in[43];
    const float* wo1 = (const float*)d_in[44];
    const float* ws0 = (const float*)d_in[45];
    const float* ws1 = (const float*)d_in[46];
    const int* nbr = (const int*)d_in[47];
    const unsigned char* maskb = (const unsigned char*)d_in[48];

    float* ws = (float*)d_ws;
    float* xi0 = ws + XI0_OFF; float* xj0 = ws + XJ0_OFF;
    float* xi1 = ws + XI1_OFF; float* xj1 = ws + XJ1_OFF;
    float* i0  = ws + INT0_OFF; float* i1 = ws + INT1_OFF;
    float* wts = ws + WTS_OFF;
    int* flagp = (int*)(ws + FLAG_OFF);

    hipLaunchKernelGGL(k_lin_in, dim3(512), dim3(256), 0, stream,
                       x0, x1, wxi0, wxj0, wxi1, wxj1, xi0, xj0, xi1, xj1);
    hipLaunchKernelGGL(k_wts, dim3(1), dim3(256), 0, stream, rp, maskb, wts, flagp);
    hipLaunchKernelGGL(k_pairsA, dim3(1024), dim3(256), 0, stream,
                       rel, b00, b01, nbr, maskb, xi0, xj0, wts, flagp, i0, i1);
    hipLaunchKernelGGL(k_pairsB, dim3(1024), dim3(256), 0, stream,
                       rel, b10, b11, nbr, maskb, xi1, xj1, wts, flagp, i0, i1);
    hipLaunchKernelGGL(k_out, dim3(1280), dim3(256), 0, stream,
                       x0, x1, i0, i1, wo0, wo1, ws0, ws1, (float*)d_out);
}

// Round 5
// 182.676 us; speedup vs baseline: 3.0882x; 1.8853x over previous
//
#include <hip/hip_runtime.h>

// ---------------------------------------------------------------------------
// DTP_5377299055222: SE(3)-equivariant conv block, B=1, N=8192, K=32, H=16
// f32 in / f32 out.
// R4 -> R5: kill k_pairsB's 700 MB spill traffic. Empirical hipcc mapping:
// __launch_bounds__(256,N) caps VGPR at ~256/N (4->64, 3->84). B's live set
// (~110-140) needs ~128 -> use (256,2). Also restructured B: '10' contracts
// xg1 into tx[8] immediately; '11' keeps bb loads inside the f-step.
// ---------------------------------------------------------------------------

#define NNODE 8192
#define KNBR  32

// workspace float offsets
#define XI0_OFF   0         // 8192*16
#define XJ0_OFF   131072
#define XI1_OFF   262144    // 8192*24
#define XJ1_OFF   458752
#define INT0_OFF  655360    // 8192*16
#define INT1_OFF  786432    // 8192*24
#define WTS_OFF   983040    // 7328 floats
#define FLAG_OFF  990400    // 1 int

// radial weight blob per pair: [w1 16][b1 16][g1 16][b2 16][g2 16][b3 C][w2t 256][w3t 16C]
// = 336 + 17C floats.  Order 00,01,10,11 ; C = 128,64,64,96.
#define BASE00 0
#define BASE01 2512
#define BASE10 3936
#define BASE11 5360
#define WTS_FLOATS 7328
#define HALF_A 3936         // floats staged by kernel A  (00+01)
#define HALF_B 3392         // floats staged by kernel B  (10+11)

static __device__ __forceinline__ float fsilu(float x) {
    return x * (1.0f / (1.0f + __expf(-x)));
}

static __device__ __forceinline__ float dot16(const float* __restrict__ w, const float* h) {
    const float4* w4 = (const float4*)w;
    float4 a = w4[0], b = w4[1], c = w4[2], d = w4[3];
    float s0 = a.x * h[0];  s0 = fmaf(a.y, h[1], s0);  s0 = fmaf(a.z, h[2],  s0);  s0 = fmaf(a.w, h[3],  s0);
    float s1 = b.x * h[4];  s1 = fmaf(b.y, h[5], s1);  s1 = fmaf(b.z, h[6],  s1);  s1 = fmaf(b.w, h[7],  s1);
    float s2 = c.x * h[8];  s2 = fmaf(c.y, h[9], s2);  s2 = fmaf(c.z, h[10], s2);  s2 = fmaf(c.w, h[11], s2);
    float s3 = d.x * h[12]; s3 = fmaf(d.y, h[13], s3); s3 = fmaf(d.z, h[14], s3);  s3 = fmaf(d.w, h[15], s3);
    return (s0 + s1) + (s2 + s3);
}

static __device__ __forceinline__ void ln16ip(float* x, const float* __restrict__ g) {
    float mu = 0.f;
#pragma unroll
    for (int h = 0; h < 16; ++h) mu += x[h];
    mu *= 0.0625f;
    float var = 0.f;
#pragma unroll
    for (int h = 0; h < 16; ++h) { float d = x[h] - mu; var = fmaf(d, d, var); }
    var *= 0.0625f;
    const float s = rsqrtf(var + 1e-5f);
#pragma unroll
    for (int h = 0; h < 16; ++h) x[h] = (x[h] - mu) * s * g[h];
}

// radial MLP layers 1+2 (incl. both LayerNorms). w = blob base (LDS).
template <int C>
static __device__ __forceinline__ void radial16(float dist, const float* __restrict__ w, float* hh) {
    float t[16];
#pragma unroll
    for (int h = 0; h < 16; ++h) t[h] = fsilu(fmaf(dist, w[h], w[16 + h]));
    ln16ip(t, w + 32);
    const float* w2t = w + 80 + C;
#pragma unroll
    for (int e = 0; e < 16; ++e) hh[e] = fsilu(w[48 + e] + dot16(w2t + e * 16, t));
    ln16ip(hh, w + 64);
}

// ---------------------------------------------------------------------------
__global__ __launch_bounds__(256) void k_lin_in(
    const float* __restrict__ x0, const float* __restrict__ x1,
    const float* __restrict__ wxi0, const float* __restrict__ wxj0,
    const float* __restrict__ wxi1, const float* __restrict__ wxj1,
    float* __restrict__ xi0, float* __restrict__ xj0,
    float* __restrict__ xi1, float* __restrict__ xj1) {
    const int t = blockIdx.x * 256 + threadIdx.x;  // 131072 threads
    const int n = t >> 4, e = t & 15;
    const float* xr = x0 + n * 16;
    float si = 0.f, sj = 0.f;
#pragma unroll
    for (int d = 0; d < 16; ++d) {
        const float xv = xr[d];
        si = fmaf(xv, wxi0[d * 16 + e], si);
        sj = fmaf(xv, wxj0[d * 16 + e], sj);
    }
    xi0[t] = si; xj0[t] = sj;
    if (e < 8) {
        const float* x1r = x1 + n * 24;
#pragma unroll
        for (int m = 0; m < 3; ++m) {
            float a = 0.f, b = 0.f;
#pragma unroll
            for (int d = 0; d < 8; ++d) {
                const float xv = x1r[d * 3 + m];
                a = fmaf(xv, wxi1[d * 8 + e], a);
                b = fmaf(xv, wxj1[d * 8 + e], b);
            }
            xi1[n * 24 + e * 3 + m] = a;
            xj1[n * 24 + e * 3 + m] = b;
        }
    }
}

// ---------------------------------------------------------------------------
struct RPtrs { const float* a[32]; };  // input order: 00,10,01,11 x (w1,b1,g1,w2,b2,g2,w3,b3)

__global__ void k_wts(RPtrs rp, const unsigned char* __restrict__ maskb,
                      float* __restrict__ wts, int* __restrict__ flagp) {
    const int tid = threadIdx.x;
    const int Cs[4]  = {128, 64, 64, 96};                 // blob order 00,01,10,11
    const int bas[4] = {BASE00, BASE01, BASE10, BASE11};
    const int rpi[4] = {0, 2, 1, 3};                      // d_in group for each blob slot
#pragma unroll
    for (int pp = 0; pp < 4; ++pp) {
        const int C = Cs[pp];
        float* dst = wts + bas[pp];
        const float* w1 = rp.a[rpi[pp] * 8 + 0]; const float* b1 = rp.a[rpi[pp] * 8 + 1];
        const float* g1 = rp.a[rpi[pp] * 8 + 2]; const float* w2 = rp.a[rpi[pp] * 8 + 3];
        const float* b2 = rp.a[rpi[pp] * 8 + 4]; const float* g2 = rp.a[rpi[pp] * 8 + 5];
        const float* w3 = rp.a[rpi[pp] * 8 + 6]; const float* b3 = rp.a[rpi[pp] * 8 + 7];
        if (tid < 16) {
            dst[tid] = w1[tid]; dst[16 + tid] = b1[tid]; dst[32 + tid] = g1[tid];
            dst[48 + tid] = b2[tid]; dst[64 + tid] = g2[tid];
        }
        for (int i = tid; i < C; i += 256) dst[80 + i] = b3[i];
        { const int e = tid >> 4, h = tid & 15; dst[80 + C + tid] = w2[h * 16 + e]; }
        for (int i = tid; i < 16 * C; i += 256) {
            const int c = i >> 4, h = i & 15;
            dst[336 + C + i] = w3[h * C + c];   // w3t[c][h]
        }
    }
    if (tid == 0) {
        // layout detect: int32 {0,1} has all bytes at (i&3)!=0 equal to 0;
        // random bools do not (P(miss) ~ 2^-48).
        int nz = 0;
        for (int i = 1; i < 64; ++i) if (i & 3) nz |= (int)maskb[i];
        *flagp = (nz != 0) ? 1 : 0;
    }
}

// ---------------------------------------------------------------------------
// Kernel A: pairs 00 (ci16,co8,nf1) and 01 (ci16,co4,nf1). One thread/(n,k).
__global__ __launch_bounds__(256, 2) void k_pairsA(
    const float* __restrict__ rel,
    const float* __restrict__ b00, const float* __restrict__ b01,
    const int* __restrict__ nbr, const unsigned char* __restrict__ maskb,
    const float* __restrict__ xi0, const float* __restrict__ xj0,
    const float* __restrict__ wts, const int* __restrict__ flagp,
    float* __restrict__ o0, float* __restrict__ o1) {
    __shared__ float4 sw4[HALF_A / 4];

    const int t = blockIdx.x * 256 + threadIdx.x;
    const int n = t >> 5;
    const int k = t & 31;
    const int j = t;

    const int idx = nbr[j];
    const float dist = rel[j];
    const int bytelay = *flagp;
    const int mv = bytelay ? (int)maskb[j] : ((const int*)maskb)[j];

    {
        const float4* g4 = (const float4*)wts;
        for (int i = threadIdx.x; i < HALF_A / 4; i += 256) sw4[i] = g4[i];
    }
    __syncthreads();
    const float* sw = (const float*)sw4;

    const float mf = mv ? 1.f : 0.f;
    float cnt = mf;
#pragma unroll
    for (int off = 16; off > 0; off >>= 1) cnt += __shfl_xor(cnt, off);
    const float inv = 1.f / fmaxf(cnt, 1.f);

    float xg0[16];
    {
        const float4* a = (const float4*)(xj0 + idx * 16);
        const float4* b = (const float4*)(xi0 + n * 16);
#pragma unroll
        for (int q = 0; q < 4; ++q) {
            const float4 u = a[q], v = b[q];
            xg0[4 * q + 0] = (u.x + v.x) * mf; xg0[4 * q + 1] = (u.y + v.y) * mf;
            xg0[4 * q + 2] = (u.z + v.z) * mf; xg0[4 * q + 3] = (u.w + v.w) * mf;
        }
    }

    float hh[16];

    // ---- pair '00' -> o0[0..7] ----
    radial16<128>(dist, sw + BASE00, hh);
    {
        const float Bv = b00[j];
        const float* b3  = sw + BASE00 + 80;
        const float* w3t = sw + BASE00 + 336 + 128;
        float acc[8];
#pragma unroll
        for (int o = 0; o < 8; ++o) acc[o] = 0.f;
#pragma unroll
        for (int i = 0; i < 16; ++i) {
            const float t0 = Bv * xg0[i];
#pragma unroll
            for (int o = 0; o < 8; ++o) {
                const int c = o * 16 + i;
                acc[o] = fmaf(b3[c] + dot16(w3t + c * 16, hh), t0, acc[o]);
            }
        }
#pragma unroll
        for (int off = 16; off > 0; off >>= 1)
#pragma unroll
            for (int o = 0; o < 8; ++o) acc[o] += __shfl_xor(acc[o], off);
        if (k == 0) {
#pragma unroll
            for (int o = 0; o < 8; ++o) o0[n * 16 + o] = acc[o] * inv;
        }
    }

    // ---- pair '01' -> o1[e=0..3] ----
    radial16<64>(dist, sw + BASE01, hh);
    {
        const float* bp = b01 + j * 3;
        const float B0 = bp[0], B1 = bp[1], B2 = bp[2];  // over mo
        const float* b3  = sw + BASE01 + 80;
        const float* w3t = sw + BASE01 + 336 + 64;
        float a1[4][3];
#pragma unroll
        for (int o = 0; o < 4; ++o) { a1[o][0] = 0.f; a1[o][1] = 0.f; a1[o][2] = 0.f; }
#pragma unroll
        for (int i = 0; i < 16; ++i) {
            const float x = xg0[i];
#pragma unroll
            for (int o = 0; o < 4; ++o) {
                const int c = o * 16 + i;
                const float rx = (b3[c] + dot16(w3t + c * 16, hh)) * x;
                a1[o][0] = fmaf(rx, B0, a1[o][0]);
                a1[o][1] = fmaf(rx, B1, a1[o][1]);
                a1[o][2] = fmaf(rx, B2, a1[o][2]);
            }
        }
#pragma unroll
        for (int off = 16; off > 0; off >>= 1)
#pragma unroll
            for (int o = 0; o < 4; ++o)
#pragma unroll
                for (int m = 0; m < 3; ++m) a1[o][m] += __shfl_xor(a1[o][m], off);
        if (k == 1) {
#pragma unroll
            for (int o = 0; o < 4; ++o)
#pragma unroll
                for (int m = 0; m < 3; ++m) o1[n * 24 + o * 3 + m] = a1[o][m] * inv;
        }
    }
}

// ---------------------------------------------------------------------------
// Kernel B: pairs 10 (ci8,co8,nf1) and 11 (ci8,co4,nf3). One thread/(n,k).
__global__ __launch_bounds__(256, 2) void k_pairsB(
    const float* __restrict__ rel,
    const float* __restrict__ b10, const float* __restrict__ b11,
    const int* __restrict__ nbr, const unsigned char* __restrict__ maskb,
    const float* __restrict__ xi1, const float* __restrict__ xj1,
    const float* __restrict__ wts, const int* __restrict__ flagp,
    float* __restrict__ o0, float* __restrict__ o1) {
    __shared__ float4 sw4[HALF_B / 4];

    const int t = blockIdx.x * 256 + threadIdx.x;
    const int n = t >> 5;
    const int k = t & 31;
    const int j = t;

    const int idx = nbr[j];
    const float dist = rel[j];
    const int bytelay = *flagp;
    const int mv = bytelay ? (int)maskb[j] : ((const int*)maskb)[j];

    {
        const float4* g4 = (const float4*)(wts + HALF_A);
        for (int i = threadIdx.x; i < HALF_B / 4; i += 256) sw4[i] = g4[i];
    }
    __syncthreads();
    const float* sw = (const float*)sw4;
    // LDS-local bases: '10' at 0, '11' at 1424
    const int L10 = 0, L11 = BASE11 - BASE10;

    const float mf = mv ? 1.f : 0.f;
    float cnt = mf;
#pragma unroll
    for (int off = 16; off > 0; off >>= 1) cnt += __shfl_xor(cnt, off);
    const float inv = 1.f / fmaxf(cnt, 1.f);

    float xg1[8][3];
    {
        const float4* a = (const float4*)(xj1 + idx * 24);
        const float4* b = (const float4*)(xi1 + n * 24);
        float tmp[24];
#pragma unroll
        for (int q = 0; q < 6; ++q) {
            const float4 u = a[q], v = b[q];
            tmp[4 * q + 0] = (u.x + v.x) * mf; tmp[4 * q + 1] = (u.y + v.y) * mf;
            tmp[4 * q + 2] = (u.z + v.z) * mf; tmp[4 * q + 3] = (u.w + v.w) * mf;
        }
#pragma unroll
        for (int i = 0; i < 8; ++i)
#pragma unroll
            for (int m = 0; m < 3; ++m) xg1[i][m] = tmp[i * 3 + m];
    }

    float hh[16];

    // ---- pair '10' -> o0[8..15] ----
    radial16<64>(dist, sw + L10, hh);
    {
        const float* bp = b10 + j * 3;
        const float B0 = bp[0], B1 = bp[1], B2 = bp[2];  // over mi
        // contract xg1 against basis immediately: tx[i] = sum_m B_m * xg1[i][m]
        float tx[8];
#pragma unroll
        for (int i = 0; i < 8; ++i)
            tx[i] = fmaf(B2, xg1[i][2], fmaf(B1, xg1[i][1], B0 * xg1[i][0]));
        const float* b3  = sw + L10 + 80;
        const float* w3t = sw + L10 + 336 + 64;
        float acc[8];
#pragma unroll
        for (int o = 0; o < 8; ++o) acc[o] = 0.f;
#pragma unroll
        for (int i = 0; i < 8; ++i) {
#pragma unroll
            for (int o = 0; o < 8; ++o) {
                const int c = o * 8 + i;
                acc[o] = fmaf(b3[c] + dot16(w3t + c * 16, hh), tx[i], acc[o]);
            }
        }
#pragma unroll
        for (int off = 16; off > 0; off >>= 1)
#pragma unroll
            for (int o = 0; o < 8; ++o) acc[o] += __shfl_xor(acc[o], off);
        if (k == 0) {
#pragma unroll
            for (int o = 0; o < 8; ++o) o0[n * 16 + 8 + o] = acc[o] * inv;
        }
    }

    // ---- pair '11' -> o1[e=4..7] ----
    radial16<96>(dist, sw + L11, hh);
    {
        const float* bp = b11 + (size_t)j * 27;  // [mo][mi][f]
        const float* b3  = sw + L11 + 80;
        const float* w3t = sw + L11 + 336 + 96;
        float a1[4][3];
#pragma unroll
        for (int o = 0; o < 4; ++o) { a1[o][0] = 0.f; a1[o][1] = 0.f; a1[o][2] = 0.f; }
#pragma unroll
        for (int f = 0; f < 3; ++f) {
            // contract basis-slice f with xg1: ty[mo] per i inside the i-loop
#pragma unroll
            for (int i = 0; i < 8; ++i) {
                const float x0v = xg1[i][0], x1v = xg1[i][1], x2v = xg1[i][2];
                const float t0 = fmaf(bp[2 * 3 + f], x2v, fmaf(bp[1 * 3 + f], x1v, bp[0 * 3 + f] * x0v));
                const float t1 = fmaf(bp[5 * 3 + f], x2v, fmaf(bp[4 * 3 + f], x1v, bp[3 * 3 + f] * x0v));
                const float t2 = fmaf(bp[8 * 3 + f], x2v, fmaf(bp[7 * 3 + f], x1v, bp[6 * 3 + f] * x0v));
#pragma unroll
                for (int o = 0; o < 4; ++o) {
                    const int c = (o * 8 + i) * 3 + f;
                    const float r = b3[c] + dot16(w3t + c * 16, hh);
                    a1[o][0] = fmaf(r, t0, a1[o][0]);
                    a1[o][1] = fmaf(r, t1, a1[o][1]);
                    a1[o][2] = fmaf(r, t2, a1[o][2]);
                }
            }
        }
#pragma unroll
        for (int off = 16; off > 0; off >>= 1)
#pragma unroll
            for (int o = 0; o < 4; ++o)
#pragma unroll
                for (int m = 0; m < 3; ++m) a1[o][m] += __shfl_xor(a1[o][m], off);
        if (k == 1) {
#pragma unroll
            for (int o = 0; o < 4; ++o)
#pragma unroll
                for (int m = 0; m < 3; ++m) o1[n * 24 + (4 + o) * 3 + m] = a1[o][m] * inv;
        }
    }
}

// ---------------------------------------------------------------------------
__global__ __launch_bounds__(256) void k_out(
    const float* __restrict__ x0, const float* __restrict__ x1,
    const float* __restrict__ i0, const float* __restrict__ i1,
    const float* __restrict__ wo0, const float* __restrict__ wo1,
    const float* __restrict__ ws0, const float* __restrict__ ws1,
    float* __restrict__ out) {
    const int t = blockIdx.x * 256 + threadIdx.x;
    if (t < 131072) {
        const int n = t >> 4, e = t & 15;
        float s = 0.f;
#pragma unroll
        for (int d = 0; d < 16; ++d) {
            s = fmaf(i0[n * 16 + d], wo0[d * 16 + e], s);
            s = fmaf(x0[n * 16 + d], ws0[d * 16 + e], s);
        }
        out[t] = s;
    } else if (t < 327680) {
        const int u = t - 131072;
        const int n = u / 24, r2 = u % 24, e = r2 / 3, m = r2 % 3;
        float s = 0.f;
#pragma unroll
        for (int d = 0; d < 8; ++d) {
            s = fmaf(i1[n * 24 + d * 3 + m], wo1[d * 8 + e], s);
            s = fmaf(x1[n * 24 + d * 3 + m], ws1[d * 8 + e], s);
        }
        out[t] = s;
    }
}

// ---------------------------------------------------------------------------
extern "C" void kernel_launch(void* const* d_in, const int* in_sizes, int n_in,
                              void* d_out, int out_size, void* d_ws, size_t ws_size,
                              hipStream_t stream) {
    const float* x0  = (const float*)d_in[0];
    const float* x1  = (const float*)d_in[1];
    const float* rel = (const float*)d_in[2];
    const float* b00 = (const float*)d_in[3];
    const float* b10 = (const float*)d_in[4];
    const float* b01 = (const float*)d_in[5];
    const float* b11 = (const float*)d_in[6];
    const float* wxi0 = (const float*)d_in[7];
    const float* wxi1 = (const float*)d_in[8];
    const float* wxj0 = (const float*)d_in[9];
    const float* wxj1 = (const float*)d_in[10];
    RPtrs rp;
    for (int i = 0; i < 32; ++i) rp.a[i] = (const float*)d_in[11 + i];
    const float* wo0 = (const float*)d_in[43];
    const float* wo1 = (const float*)d_in[44];
    const float* ws0 = (const float*)d_in[45];
    const float* ws1 = (const float*)d_in[46];
    const int* nbr = (const int*)d_in[47];
    const unsigned char* maskb = (const unsigned char*)d_in[48];

    float* ws = (float*)d_ws;
    float* xi0 = ws + XI0_OFF; float* xj0 = ws + XJ0_OFF;
    float* xi1 = ws + XI1_OFF; float* xj1 = ws + XJ1_OFF;
    float* i0  = ws + INT0_OFF; float* i1 = ws + INT1_OFF;
    float* wts = ws + WTS_OFF;
    int* flagp = (int*)(ws + FLAG_OFF);

    hipLaunchKernelGGL(k_lin_in, dim3(512), dim3(256), 0, stream,
                       x0, x1, wxi0, wxj0, wxi1, wxj1, xi0, xj0, xi1, xj1);
    hipLaunchKernelGGL(k_wts, dim3(1), dim3(256), 0, stream, rp, maskb, wts, flagp);
    hipLaunchKernelGGL(k_pairsA, dim3(1024), dim3(256), 0, stream,
                       rel, b00, b01, nbr, maskb, xi0, xj0, wts, flagp, i0, i1);
    hipLaunchKernelGGL(k_pairsB, dim3(1024), dim3(256), 0, stream,
                       rel, b10, b11, nbr, maskb, xi1, xj1, wts, flagp, i0, i1);
    hipLaunchKernelGGL(k_out, dim3(1280), dim3(256), 0, stream,
                       x0, x1, i0, i1, wo0, wo1, ws0, ws1, (float*)d_out);
}